// Round 4
// baseline (625.653 us; speedup 1.0000x reference)
//
#include <hip/hip_runtime.h>
#include <hip/hip_bf16.h>
#include <float.h>

// Problem constants
#define NPIX   32768      // B*H*W
#define CDIM   128
#define KCB    8192
#define TAUG   0.45f      // packed group-gap guard (f16 err + 2x quant)
#define TAUF   0.01f      // exact fp32 gap guard (fp32-z vs fp64-z)
#define RCAP   8192

typedef _Float16 f16x8 __attribute__((ext_vector_type(8)));
typedef float    f32x16 __attribute__((ext_vector_type(16)));

// ws layout (bytes)
#define WS_EMBFH   0           // 2,359,296  (256 tiles x 9 steps x 64 lanes x 16B)
#define WS_E2      2359296     // 8192 f32
#define WS_ZWS     2392064     // 32768*128 f32 = 16,777,216
#define WS_CAND    19169280    // 32768 float4 = 524,288
#define WS_IDX     19693568    // 32768 i32
#define WS_RLIST   19824640    // 8192 i32
#define WS_COUNTS  19857408    // 8192 f32
#define WS_LOSS    19890176    // 1 f32
#define WS_RCNT    19890180    // 1 i32
#define WS_ZERO_OFF 19857408
#define WS_ZERO_LEN 32776

// d_out layout (f32): [0]=loss, [1..4194304]=out BCHW, [4194305]=perplexity, [4194306..]=idx
#define OUT_OFF_OUT  1
#define OUT_OFF_PERP 4194305
#define OUT_OFF_IDX  4194306

// ---------------- K0: e2[k] = sum_c emb[k][c]^2 ----------------
__global__ __launch_bounds__(256) void k_e2(const float* __restrict__ emb, float* __restrict__ e2) {
    int t = threadIdx.x;
    int wv = t >> 6, l = t & 63;
    int k = blockIdx.x * 4 + wv;
    const float2 v = *(const float2*)&emb[(size_t)k * 128 + l * 2];
    float s = v.x * v.x + v.y * v.y;
    #pragma unroll
    for (int o = 32; o; o >>= 1) s += __shfl_down(s, o, 64);
    if (l == 0) e2[k] = s;
}

// ---------------- K1: fragment-ordered -2*emb (f16), e2+512 hi/lo fold in step 8 ----------------
// element (g,s,lane,j): code m = g*32 + (lane&31), k-slot = s*16 + (lane>>5)*8 + j
__global__ __launch_bounds__(256) void k_prep(const float* __restrict__ emb, const float* __restrict__ e2,
                                              _Float16* __restrict__ embFh) {
    int tid = blockIdx.x * 256 + threadIdx.x;   // < 147456 = 8192*18
    int m = tid / 18, r = tid % 18;
    int s = r >> 1, h = r & 1;
    f16x8 hv;
    #pragma unroll
    for (int j = 0; j < 8; ++j) hv[j] = (_Float16)0.0f;
    if (s < 8) {
        int c0 = s * 16 + h * 8;
        const float4 a = *(const float4*)&emb[(size_t)m * 128 + c0];
        const float4 b = *(const float4*)&emb[(size_t)m * 128 + c0 + 4];
        float vals[8] = {a.x, a.y, a.z, a.w, b.x, b.y, b.z, b.w};
        #pragma unroll
        for (int j = 0; j < 8; ++j) hv[j] = (_Float16)(-2.0f * vals[j]);
    } else if (h == 0) {
        float v = e2[m] + 512.0f;    // offset keeps packed values > 0 (z2 dropped)
        _Float16 eh = (_Float16)v;
        hv[0] = eh;                  // x B8[0]=1
        hv[1] = (_Float16)(v - (float)eh);   // x B8[1]=1
    }
    size_t base = (((size_t)(m >> 5) * 9 + s) * 64 + (m & 31) + h * 32) * 8;
    *(f16x8*)&embFh[base] = hv;
}

// ---------------- K2: fused linear + MFMA + packed group-min top-3 ----------------
__global__ __launch_bounds__(256, 2) void k_main(
    const float* __restrict__ x, const float* __restrict__ Wl, const float* __restrict__ bl,
    const _Float16* __restrict__ embFh,
    float* __restrict__ zws, float4* __restrict__ cand)
{
    __shared__ __align__(16) float As[64 * 132];   // z [p][c], pitch 132
    __shared__ __align__(16) float Xs[64 * 66];    // x staging / merge scratch

    const int t  = threadIdx.x;
    const int n0 = blockIdx.x * 64;
    const int b  = n0 >> 10;
    const int hw0 = n0 & 1023;

    // ===== Phase 1: z for 64 pixels =====
    {
        const int p = t & 63, ig = t >> 6;
        float accz[32];
        const float4* bl4 = (const float4*)(bl + ig * 32);
        #pragma unroll
        for (int q = 0; q < 8; ++q) {
            float4 v = bl4[q];
            accz[4*q+0] = v.x; accz[4*q+1] = v.y; accz[4*q+2] = v.z; accz[4*q+3] = v.w;
        }
        for (int hf = 0; hf < 2; ++hf) {
            __syncthreads();
            for (int r = 0; r < 16; ++r) {
                int lin = r * 256 + t;
                int cc = lin >> 6, pp = lin & 63;
                Xs[cc * 66 + pp] = x[(size_t)(b * 128 + hf * 64 + cc) * 1024 + hw0 + pp];
            }
            __syncthreads();
            for (int cc4 = 0; cc4 < 16; ++cc4) {
                float xv0 = Xs[(cc4*4+0) * 66 + p];
                float xv1 = Xs[(cc4*4+1) * 66 + p];
                float xv2 = Xs[(cc4*4+2) * 66 + p];
                float xv3 = Xs[(cc4*4+3) * 66 + p];
                #pragma unroll
                for (int ii = 0; ii < 32; ++ii) {
                    const float4 w4 = *(const float4*)&Wl[(size_t)(ig*32+ii) * 128 + hf*64 + cc4*4];
                    float a = accz[ii];
                    a = fmaf(w4.x, xv0, a);
                    a = fmaf(w4.y, xv1, a);
                    a = fmaf(w4.z, xv2, a);
                    a = fmaf(w4.w, xv3, a);
                    accz[ii] = a;
                }
            }
        }
        float4* ao = (float4*)&As[p * 132 + ig * 32];
        float4* zo = (float4*)(zws + (size_t)(n0 + p) * 128 + ig * 32);
        #pragma unroll
        for (int q = 0; q < 8; ++q) {
            float4 v = make_float4(accz[4*q+0], accz[4*q+1], accz[4*q+2], accz[4*q+3]);
            ao[q] = v;
            zo[q] = v;
        }
    }
    __syncthreads();

    // ===== Phase 2: B fragments (z f16) + constant fold step =====
    const int l = t & 63, w = t >> 6;
    const int half = l >> 5, pcol = l & 31;
    f16x8 B0[9], B1[9];
    #pragma unroll
    for (int nt = 0; nt < 2; ++nt) {
        int p = nt * 32 + pcol;
        #pragma unroll
        for (int s = 0; s < 8; ++s) {
            const float* zp = &As[p * 132 + s * 16 + half * 8];
            float4 v0 = *(const float4*)zp;
            float4 v1 = *(const float4*)(zp + 4);
            float vals[8] = {v0.x, v0.y, v0.z, v0.w, v1.x, v1.y, v1.z, v1.w};
            f16x8 hh;
            #pragma unroll
            for (int j2 = 0; j2 < 8; ++j2) hh[j2] = (_Float16)vals[j2];
            if (nt == 0) B0[s] = hh; else B1[s] = hh;
        }
    }
    {
        f16x8 b8;
        #pragma unroll
        for (int j2 = 0; j2 < 8; ++j2) b8[j2] = (_Float16)0.0f;
        if (half == 0) { b8[0] = (_Float16)1.0f; b8[1] = (_Float16)1.0f; }
        B0[8] = b8; B1[8] = b8;
    }

    // ===== Phase 3: K-loop, explicit even/odd A double-buffer, 4 acc chains =====
    auto tree16 = [](const f32x16& v) -> float {
        float a = fminf(fminf(v[0], v[1]), fminf(v[2], v[3]));
        float bb = fminf(fminf(v[4], v[5]), fminf(v[6], v[7]));
        float c = fminf(fminf(v[8], v[9]), fminf(v[10], v[11]));
        float d = fminf(fminf(v[12], v[13]), fminf(v[14], v[15]));
        return fminf(fminf(a, bb), fminf(c, d));
    };

    float gv1 = 3e38f, gv2 = 3e38f, gv3 = 3e38f;   // tile0: px = pcol
    float hv1 = 3e38f, hv2 = 3e38f, hv3 = 3e38f;   // tile1: px = 32+pcol
    const f16x8* Ahp = (const f16x8*)embFh;
    f16x8 aE[9], aO[9];
    {
        const f16x8* P = Ahp + (size_t)w * 576 + l;
        #pragma unroll
        for (int s = 0; s < 9; ++s) aE[s] = P[s * 64];
    }
    {
        const f16x8* P = Ahp + (size_t)(w + 4) * 576 + l;
        #pragma unroll
        for (int s = 0; s < 9; ++s) aO[s] = P[s * 64];
    }
    uint32_t idv = (uint32_t)((w << 1) | half);

    for (int g = w; g < 256; g += 8) {
        // ---- even sub-iter: groups id = idv ----
        {
            f32x16 c00 = {}, c01 = {}, c10 = {}, c11 = {};
            #pragma unroll
            for (int s = 0; s < 9; ++s) {
                if (s & 1) {
                    c01 = __builtin_amdgcn_mfma_f32_32x32x16_f16(aE[s], B0[s], c01, 0, 0, 0);
                    c11 = __builtin_amdgcn_mfma_f32_32x32x16_f16(aE[s], B1[s], c11, 0, 0, 0);
                } else {
                    c00 = __builtin_amdgcn_mfma_f32_32x32x16_f16(aE[s], B0[s], c00, 0, 0, 0);
                    c10 = __builtin_amdgcn_mfma_f32_32x32x16_f16(aE[s], B1[s], c10, 0, 0, 0);
                }
            }
            f32x16 s0, s1;
            #pragma unroll
            for (int r = 0; r < 16; ++r) { s0[r] = c00[r] + c01[r]; s1[r] = c10[r] + c11[r]; }
            float m0 = tree16(s0), m1 = tree16(s1);
            float f0 = __uint_as_float((__float_as_uint(m0) & 0xFFFFFE00u) | idv);
            float f1 = __uint_as_float((__float_as_uint(m1) & 0xFFFFFE00u) | idv);
            float x1 = fmaxf(gv1, f0); gv1 = fminf(gv1, f0);
            float x2 = fmaxf(gv2, x1); gv2 = fminf(gv2, x1); gv3 = fminf(gv3, x2);
            float y1 = fmaxf(hv1, f1); hv1 = fminf(hv1, f1);
            float y2 = fmaxf(hv2, y1); hv2 = fminf(hv2, y1); hv3 = fminf(hv3, y2);
        }
        {   // refill even buffer for g+8 (aE dead now; odd body covers latency)
            int gn = (g + 8 < 256) ? (g + 8) : w;
            const f16x8* P = Ahp + (size_t)gn * 576 + l;
            #pragma unroll
            for (int s = 0; s < 9; ++s) aE[s] = P[s * 64];
        }
        // ---- odd sub-iter: groups id = idv + 8 ----
        {
            f32x16 c00 = {}, c01 = {}, c10 = {}, c11 = {};
            #pragma unroll
            for (int s = 0; s < 9; ++s) {
                if (s & 1) {
                    c01 = __builtin_amdgcn_mfma_f32_32x32x16_f16(aO[s], B0[s], c01, 0, 0, 0);
                    c11 = __builtin_amdgcn_mfma_f32_32x32x16_f16(aO[s], B1[s], c11, 0, 0, 0);
                } else {
                    c00 = __builtin_amdgcn_mfma_f32_32x32x16_f16(aO[s], B0[s], c00, 0, 0, 0);
                    c10 = __builtin_amdgcn_mfma_f32_32x32x16_f16(aO[s], B1[s], c10, 0, 0, 0);
                }
            }
            f32x16 s0, s1;
            #pragma unroll
            for (int r = 0; r < 16; ++r) { s0[r] = c00[r] + c01[r]; s1[r] = c10[r] + c11[r]; }
            float m0 = tree16(s0), m1 = tree16(s1);
            uint32_t ido = idv + 8u;
            float f0 = __uint_as_float((__float_as_uint(m0) & 0xFFFFFE00u) | ido);
            float f1 = __uint_as_float((__float_as_uint(m1) & 0xFFFFFE00u) | ido);
            float x1 = fmaxf(gv1, f0); gv1 = fminf(gv1, f0);
            float x2 = fmaxf(gv2, x1); gv2 = fminf(gv2, x1); gv3 = fminf(gv3, x2);
            float y1 = fmaxf(hv1, f1); hv1 = fminf(hv1, f1);
            float y2 = fmaxf(hv2, y1); hv2 = fminf(hv2, y1); hv3 = fminf(hv3, y2);
        }
        {   // refill odd buffer for g+12
            int gn = (g + 12 < 256) ? (g + 12) : w;
            const f16x8* P = Ahp + (size_t)gn * 576 + l;
            #pragma unroll
            for (int s = 0; s < 9; ++s) aO[s] = P[s * 64];
        }
        idv += 16u;
    }

    // ===== Phase 4: cross-wave merge per pixel, write cand =====
    __syncthreads();
    float* Ms = Xs;   // [64 px][8 slots][3]
    const int slot = (w << 1) | half;
    Ms[(pcol * 8 + slot) * 3 + 0] = gv1;
    Ms[(pcol * 8 + slot) * 3 + 1] = gv2;
    Ms[(pcol * 8 + slot) * 3 + 2] = gv3;
    Ms[((32 + pcol) * 8 + slot) * 3 + 0] = hv1;
    Ms[((32 + pcol) * 8 + slot) * 3 + 1] = hv2;
    Ms[((32 + pcol) * 8 + slot) * 3 + 2] = hv3;
    __syncthreads();
    if (t < 64) {
        float g1 = 3e38f, g2 = 3e38f, g3 = 3e38f;
        #pragma unroll
        for (int s = 0; s < 24; ++s) {
            float v = Ms[t * 24 + s];
            float a1 = fmaxf(g1, v); g1 = fminf(g1, v);
            float a2 = fmaxf(g2, a1); g2 = fminf(g2, a1);
            g3 = fminf(g3, a2);
        }
        cand[n0 + t] = make_float4(g1, g2, g3, 0.f);
    }
}

// ---------------- K3: recovery — exact fp32 over top-2 groups, flag near-ties ----------------
__global__ __launch_bounds__(256) void k_rec(
    const float* __restrict__ zws, const float* __restrict__ emb,
    const float4* __restrict__ cand, int* __restrict__ idxws,
    float* __restrict__ out_idxf, float* __restrict__ losssum,
    int* __restrict__ rlist, int* __restrict__ rcnt)
{
    __shared__ __align__(16) float zs[16 * 132];
    __shared__ float2 cd[16 * 32];
    const int t = threadIdx.x;
    const int pl = t >> 4, j = t & 15;
    const int n = blockIdx.x * 16 + pl;
    {
        const size_t base = (size_t)blockIdx.x * 2048;
        #pragma unroll
        for (int r = 0; r < 2; ++r) {
            int off = r * 1024 + t * 4;
            float4 v = *(const float4*)&zws[base + off];
            int p = off >> 7, c = off & 127;
            *(float4*)&zs[p * 132 + c] = v;
        }
    }
    float4 cv = cand[n];
    __syncthreads();
    const int rc = (j & 3) + 8 * (j >> 2);
    #pragma unroll
    for (int q = 0; q < 2; ++q) {
        uint32_t bits = __float_as_uint(q == 0 ? cv.x : cv.y);
        int id = (int)(bits & 511u);
        int m = (id >> 1) * 32 + ((id & 1) << 2) + rc;
        float acc = 0.f;
        const float4* ep = (const float4*)&emb[(size_t)m * 128];
        const float* zp = &zs[pl * 132];
        #pragma unroll 8
        for (int c4 = 0; c4 < 32; ++c4) {
            float4 e4 = ep[c4];
            float4 z4 = *(const float4*)&zp[c4 * 4];
            float d0 = z4.x - e4.x, d1 = z4.y - e4.y, d2 = z4.z - e4.z, d3 = z4.w - e4.w;
            acc = fmaf(d0, d0, fmaf(d1, d1, fmaf(d2, d2, fmaf(d3, d3, acc))));
        }
        cd[pl * 32 + j * 2 + q] = make_float2(acc, (float)m);
    }
    __syncthreads();
    if (j == 0) {
        float d1 = 3e38f, d2 = 3e38f; int i1 = 0, i2 = 0;
        for (int s = 0; s < 32; ++s) {
            float2 e = cd[pl * 32 + s];
            float dv = e.x; int iv = (int)e.y;
            if (dv < d1 || (dv == d1 && iv < i1)) { d2 = d1; i2 = i1; d1 = dv; i1 = iv; }
            else if (dv < d2 || (dv == d2 && iv < i2)) { d2 = dv; i2 = iv; }
        }
        idxws[n] = i1;
        out_idxf[n] = (float)i1;
        atomicAdd(losssum, d1);
        if ((cv.z - cv.x) < TAUG || (d2 - d1) < TAUF) {
            int s = atomicAdd(rcnt, 1);
            if (s < RCAP) rlist[s] = n;
        }
    }
}

// ---------------- K4: full exact scan for flagged pixels ----------------
__global__ __launch_bounds__(128) void k_scan(
    const float* __restrict__ x, const float* __restrict__ Wl, const float* __restrict__ bl,
    const float* __restrict__ emb, const int* __restrict__ rcnt, const int* __restrict__ rlist,
    int* __restrict__ idxws, float* __restrict__ out_idxf)
{
    __shared__ double xs[128];
    __shared__ double zd[128];
    __shared__ __align__(16) float zf[128];
    __shared__ double red[128];
    __shared__ float red32[128];
    __shared__ int nl;
    __shared__ int clist[16];
    int cnt = *rcnt; if (cnt > RCAP) cnt = RCAP;
    const int t = threadIdx.x;
    for (int e = blockIdx.x; e < cnt; e += gridDim.x) {
        const int n = rlist[e];
        const int b = n >> 10, hw = n & 1023;
        __syncthreads();
        xs[t] = (double)x[(size_t)(b * 128 + t) * 1024 + hw];
        if (t == 0) nl = 0;
        __syncthreads();
        double z = (double)bl[t];
        for (int c = 0; c < 128; ++c) z = fma((double)Wl[(size_t)t * 128 + c], xs[c], z);
        zd[t] = z; zf[t] = (float)z;
        __syncthreads();
        // fp32 full scan for the block minimum
        float dmin = 3e38f;
        for (int k = t; k < KCB; k += 128) {
            const float4* ep = (const float4*)&emb[(size_t)k * 128];
            float d = 0.f;
            #pragma unroll 8
            for (int c4 = 0; c4 < 32; ++c4) {
                float4 e4 = ep[c4];
                float4 z4 = *(const float4*)&zf[c4 * 4];
                float d0 = z4.x - e4.x, d1 = z4.y - e4.y, d2 = z4.z - e4.z, d3 = z4.w - e4.w;
                d = fmaf(d0, d0, fmaf(d1, d1, fmaf(d2, d2, fmaf(d3, d3, d))));
            }
            dmin = fminf(dmin, d);
        }
        red32[t] = dmin; __syncthreads();
        for (int o = 64; o; o >>= 1) { if (t < o) red32[t] = fminf(red32[t], red32[t + o]); __syncthreads(); }
        float dblk = red32[0];
        // collect shortlist
        for (int k = t; k < KCB; k += 128) {
            const float4* ep = (const float4*)&emb[(size_t)k * 128];
            float d = 0.f;
            #pragma unroll 8
            for (int c4 = 0; c4 < 32; ++c4) {
                float4 e4 = ep[c4];
                float4 z4 = *(const float4*)&zf[c4 * 4];
                float d0 = z4.x - e4.x, d1 = z4.y - e4.y, d2 = z4.z - e4.z, d3 = z4.w - e4.w;
                d = fmaf(d0, d0, fmaf(d1, d1, fmaf(d2, d2, fmaf(d3, d3, d))));
            }
            if (d < dblk + 0.05f) { int p = atomicAdd(&nl, 1); if (p < 16) clist[p] = k; }
        }
        __syncthreads();
        int c2 = nl < 16 ? nl : 16;
        double bd = 1e300; int bi = KCB;
        for (int q = 0; q < c2; ++q) {
            int k = clist[q];
            double df = zd[t] - (double)emb[(size_t)k * 128 + t];
            red[t] = df * df; __syncthreads();
            for (int o = 64; o; o >>= 1) { if (t < o) red[t] += red[t + o]; __syncthreads(); }
            double d = red[0]; __syncthreads();
            if (d < bd || (d == bd && k < bi)) { bd = d; bi = k; }
        }
        if (t == 0) { idxws[n] = bi; out_idxf[n] = (float)bi; }
    }
}

// ---------------- K5: gather + transpose + histogram ----------------
__global__ __launch_bounds__(256) void k_out(
    const float* __restrict__ emb, const int* __restrict__ idxws,
    float* __restrict__ outp /* d_out + 1 */, float* __restrict__ counts)
{
    const int t = threadIdx.x;
    const int b = blockIdx.x >> 2, h0 = (blockIdx.x & 3) << 3;
    const int n = b * 1024 + h0 * 32 + t;
    const int id = idxws[n];
    atomicAdd(&counts[id], 1.0f);
    const float4* ep = (const float4*)&emb[(size_t)id * 128];
    float* ob = outp + (size_t)b * 131072 + h0 * 32 + t;
    #pragma unroll 4
    for (int c4 = 0; c4 < 32; ++c4) {
        float4 v = ep[c4];
        ob[(c4 * 4 + 0) * 1024] = v.x;
        ob[(c4 * 4 + 1) * 1024] = v.y;
        ob[(c4 * 4 + 2) * 1024] = v.z;
        ob[(c4 * 4 + 3) * 1024] = v.w;
    }
}

// ---------------- K6: finalize loss + perplexity ----------------
__global__ __launch_bounds__(256) void k_final(
    const float* __restrict__ counts, const float* __restrict__ losssum, float* __restrict__ d_out)
{
    const int t = threadIdx.x;
    float ent = 0.f;
    for (int k = t; k < KCB; k += 256) {
        float p = counts[k] * (1.0f / 32768.0f);
        ent -= p * logf(p + 1e-10f);
    }
    #pragma unroll
    for (int o = 32; o; o >>= 1) ent += __shfl_down(ent, o, 64);
    __shared__ float wred[4];
    if ((t & 63) == 0) wred[t >> 6] = ent;
    __syncthreads();
    if (t == 0) {
        float e = wred[0] + wred[1] + wred[2] + wred[3];
        d_out[0] = 1.25f * (*losssum) * (1.0f / 4194304.0f);
        d_out[OUT_OFF_PERP] = expf(e);
    }
}

extern "C" void kernel_launch(void* const* d_in, const int* in_sizes, int n_in,
                              void* d_out, int out_size, void* d_ws, size_t ws_size,
                              hipStream_t stream) {
    (void)in_sizes; (void)n_in; (void)out_size; (void)ws_size;
    const float* x   = (const float*)d_in[0];
    const float* Wl  = (const float*)d_in[1];
    const float* bl  = (const float*)d_in[2];
    const float* emb = (const float*)d_in[3];
    float* out = (float*)d_out;
    char*  ws  = (char*)d_ws;

    _Float16* embFh = (_Float16*)(ws + WS_EMBFH);
    float* e2      = (float*)(ws + WS_E2);
    float* zws     = (float*)(ws + WS_ZWS);
    float4* cand   = (float4*)(ws + WS_CAND);
    int*   idxws   = (int*)  (ws + WS_IDX);
    int*   rlist   = (int*)  (ws + WS_RLIST);
    float* counts  = (float*)(ws + WS_COUNTS);
    float* losssum = (float*)(ws + WS_LOSS);
    int*   rcnt    = (int*)  (ws + WS_RCNT);

    hipMemsetAsync(ws + WS_ZERO_OFF, 0, WS_ZERO_LEN, stream);

    k_e2<<<KCB / 4, 256, 0, stream>>>(emb, e2);
    k_prep<<<576, 256, 0, stream>>>(emb, e2, embFh);
    k_main<<<NPIX / 64, 256, 0, stream>>>(x, Wl, bl, embFh, zws, cand);
    k_rec<<<NPIX / 16, 256, 0, stream>>>(zws, emb, cand, idxws, out + OUT_OFF_IDX,
                                         losssum, rlist, rcnt);
    k_scan<<<256, 128, 0, stream>>>(x, Wl, bl, emb, rcnt, rlist, idxws, out + OUT_OFF_IDX);
    k_out<<<128, 256, 0, stream>>>(emb, idxws, out + OUT_OFF_OUT, counts);
    k_final<<<1, 256, 0, stream>>>(counts, losssum, out);
}

// Round 6
// 550.859 us; speedup vs baseline: 1.1358x; 1.1358x over previous
//
#include <hip/hip_runtime.h>
#include <hip/hip_bf16.h>
#include <float.h>

// Problem constants
#define NPIX   32768      // B*H*W
#define CDIM   128
#define KCB    8192
#define EPS_STOP 0.30f    // mask quant (0.031) + f16-dot error bound
#define TAUF   0.012f     // exact fp32 gap guard -> fp64 arbitration
#define RCAP   8192

typedef _Float16 f16x8 __attribute__((ext_vector_type(8)));
typedef float    f32x16 __attribute__((ext_vector_type(16)));

// ws layout (bytes)
#define WS_EMBFH   0           // 2,359,296
#define WS_E2      2359296     // 8192 f32
#define WS_ZWS     2392064     // 16,777,216
#define WS_CAND    19169280    // 32768 * 32 B = 1,048,576
#define WS_IDX     20217856    // 131072
#define WS_RLIST   20348928    // 32768
#define WS_COUNTS  20381696    // 32768
#define WS_LOSS    20414464    // 4
#define WS_RCNT    20414468    // 4
#define WS_ZERO_OFF 20381696
#define WS_ZERO_LEN 32776

// d_out layout (f32): [0]=loss, [1..4194304]=out BCHW, [4194305]=perplexity, [4194306..]=idx
#define OUT_OFF_OUT  1
#define OUT_OFF_PERP 4194305
#define OUT_OFF_IDX  4194306

__device__ __forceinline__ void ins6(float f, float v[6]) {
    float a = fmaxf(v[0], f); v[0] = fminf(v[0], f);
    float b = fmaxf(v[1], a); v[1] = fminf(v[1], a);
    a = fmaxf(v[2], b); v[2] = fminf(v[2], b);
    b = fmaxf(v[3], a); v[3] = fminf(v[3], a);
    a = fmaxf(v[4], b); v[4] = fminf(v[4], b);
    v[5] = fminf(v[5], a);
}

// ---------------- K0: e2[k] = sum_c emb[k][c]^2 ----------------
__global__ __launch_bounds__(256) void k_e2(const float* __restrict__ emb, float* __restrict__ e2) {
    int t = threadIdx.x;
    int wv = t >> 6, l = t & 63;
    int k = blockIdx.x * 4 + wv;
    const float2 v = *(const float2*)&emb[(size_t)k * 128 + l * 2];
    float s = v.x * v.x + v.y * v.y;
    #pragma unroll
    for (int o = 32; o; o >>= 1) s += __shfl_down(s, o, 64);
    if (l == 0) e2[k] = s;
}

// ---------------- K1: fragment-ordered -2*emb (f16), e2+512 hi/lo fold in step 8 ----------------
__global__ __launch_bounds__(256) void k_prep(const float* __restrict__ emb, const float* __restrict__ e2,
                                              _Float16* __restrict__ embFh) {
    int tid = blockIdx.x * 256 + threadIdx.x;   // < 147456 = 8192*18
    int m = tid / 18, r = tid % 18;
    int s = r >> 1, h = r & 1;
    f16x8 hv;
    #pragma unroll
    for (int j = 0; j < 8; ++j) hv[j] = (_Float16)0.0f;
    if (s < 8) {
        int c0 = s * 16 + h * 8;
        const float4 a = *(const float4*)&emb[(size_t)m * 128 + c0];
        const float4 b = *(const float4*)&emb[(size_t)m * 128 + c0 + 4];
        float vals[8] = {a.x, a.y, a.z, a.w, b.x, b.y, b.z, b.w};
        #pragma unroll
        for (int j = 0; j < 8; ++j) hv[j] = (_Float16)(-2.0f * vals[j]);
    } else if (h == 0) {
        float v = e2[m] + 512.0f;    // offset keeps packed values > 0 (z2 dropped)
        _Float16 eh = (_Float16)v;
        hv[0] = eh;                  // x B8[0]=1
        hv[1] = (_Float16)(v - (float)eh);   // x B8[1]=1
    }
    size_t base = (((size_t)(m >> 5) * 9 + s) * 64 + (m & 31) + h * 32) * 8;
    *(f16x8*)&embFh[base] = hv;
}

// ---------------- K2: fused linear + MFMA + packed group-min top-6 ----------------
__global__ __launch_bounds__(256, 2) void k_main(
    const float* __restrict__ x, const float* __restrict__ Wl, const float* __restrict__ bl,
    const _Float16* __restrict__ embFh,
    float* __restrict__ zws, float4* __restrict__ cand)
{
    __shared__ __align__(16) float As[64 * 132];   // z [p][c], pitch 132
    __shared__ __align__(16) float Xs[64 * 66];    // x staging / merge scratch
    __shared__ float z2p[256];                      // z^2 partials [p][ig]

    const int t  = threadIdx.x;
    const int n0 = blockIdx.x * 64;
    const int b  = n0 >> 10;
    const int hw0 = n0 & 1023;

    // ===== Phase 1: z for 64 pixels =====
    {
        const int p = t & 63, ig = t >> 6;
        float accz[32];
        const float4* bl4 = (const float4*)(bl + ig * 32);
        #pragma unroll
        for (int q = 0; q < 8; ++q) {
            float4 v = bl4[q];
            accz[4*q+0] = v.x; accz[4*q+1] = v.y; accz[4*q+2] = v.z; accz[4*q+3] = v.w;
        }
        for (int hf = 0; hf < 2; ++hf) {
            __syncthreads();
            for (int r = 0; r < 16; ++r) {
                int lin = r * 256 + t;
                int cc = lin >> 6, pp = lin & 63;
                Xs[cc * 66 + pp] = x[(size_t)(b * 128 + hf * 64 + cc) * 1024 + hw0 + pp];
            }
            __syncthreads();
            for (int cc4 = 0; cc4 < 16; ++cc4) {
                float xv0 = Xs[(cc4*4+0) * 66 + p];
                float xv1 = Xs[(cc4*4+1) * 66 + p];
                float xv2 = Xs[(cc4*4+2) * 66 + p];
                float xv3 = Xs[(cc4*4+3) * 66 + p];
                #pragma unroll
                for (int ii = 0; ii < 32; ++ii) {
                    const float4 w4 = *(const float4*)&Wl[(size_t)(ig*32+ii) * 128 + hf*64 + cc4*4];
                    float a = accz[ii];
                    a = fmaf(w4.x, xv0, a);
                    a = fmaf(w4.y, xv1, a);
                    a = fmaf(w4.z, xv2, a);
                    a = fmaf(w4.w, xv3, a);
                    accz[ii] = a;
                }
            }
        }
        float ssq = 0.f;
        float4* ao = (float4*)&As[p * 132 + ig * 32];
        float4* zo = (float4*)(zws + (size_t)(n0 + p) * 128 + ig * 32);
        #pragma unroll
        for (int q = 0; q < 8; ++q) {
            float4 v = make_float4(accz[4*q+0], accz[4*q+1], accz[4*q+2], accz[4*q+3]);
            ao[q] = v;
            zo[q] = v;
            ssq = fmaf(v.x, v.x, fmaf(v.y, v.y, fmaf(v.z, v.z, fmaf(v.w, v.w, ssq))));
        }
        z2p[p * 4 + ig] = ssq;
    }
    __syncthreads();

    // ===== Phase 2: B fragments (z f16) + constant fold step =====
    const int l = t & 63, w = t >> 6;
    const int half = l >> 5, pcol = l & 31;
    f16x8 B0[9], B1[9];
    #pragma unroll
    for (int nt = 0; nt < 2; ++nt) {
        int p = nt * 32 + pcol;
        #pragma unroll
        for (int s = 0; s < 8; ++s) {
            const float* zp = &As[p * 132 + s * 16 + half * 8];
            float4 v0 = *(const float4*)zp;
            float4 v1 = *(const float4*)(zp + 4);
            float vals[8] = {v0.x, v0.y, v0.z, v0.w, v1.x, v1.y, v1.z, v1.w};
            f16x8 hh;
            #pragma unroll
            for (int j2 = 0; j2 < 8; ++j2) hh[j2] = (_Float16)vals[j2];
            if (nt == 0) B0[s] = hh; else B1[s] = hh;
        }
    }
    {
        f16x8 b8;
        #pragma unroll
        for (int j2 = 0; j2 < 8; ++j2) b8[j2] = (_Float16)0.0f;
        if (half == 0) { b8[0] = (_Float16)1.0f; b8[1] = (_Float16)1.0f; }
        B0[8] = b8; B1[8] = b8;
    }

    // ===== Phase 3: K-loop, even/odd A double-buffer, 4 acc chains, top-6 groups =====
    auto tree16 = [](const f32x16& v) -> float {
        float a = fminf(fminf(v[0], v[1]), fminf(v[2], v[3]));
        float bb = fminf(fminf(v[4], v[5]), fminf(v[6], v[7]));
        float c = fminf(fminf(v[8], v[9]), fminf(v[10], v[11]));
        float d = fminf(fminf(v[12], v[13]), fminf(v[14], v[15]));
        return fminf(fminf(a, bb), fminf(c, d));
    };

    float gv[6] = {3e38f, 3e38f, 3e38f, 3e38f, 3e38f, 3e38f};   // tile0: px = pcol
    float hv[6] = {3e38f, 3e38f, 3e38f, 3e38f, 3e38f, 3e38f};   // tile1: px = 32+pcol
    const f16x8* Ahp = (const f16x8*)embFh;
    f16x8 aE[9], aO[9];
    {
        const f16x8* P = Ahp + (size_t)w * 576 + l;
        #pragma unroll
        for (int s = 0; s < 9; ++s) aE[s] = P[s * 64];
    }
    {
        const f16x8* P = Ahp + (size_t)(w + 4) * 576 + l;
        #pragma unroll
        for (int s = 0; s < 9; ++s) aO[s] = P[s * 64];
    }
    uint32_t idv = (uint32_t)((w << 1) | half);

    for (int g = w; g < 256; g += 8) {
        // ---- even sub-iter: tile g, id = idv ----
        {
            f32x16 c00 = {}, c01 = {}, c10 = {}, c11 = {};
            #pragma unroll
            for (int s = 0; s < 9; ++s) {
                if (s & 1) {
                    c01 = __builtin_amdgcn_mfma_f32_32x32x16_f16(aE[s], B0[s], c01, 0, 0, 0);
                    c11 = __builtin_amdgcn_mfma_f32_32x32x16_f16(aE[s], B1[s], c11, 0, 0, 0);
                } else {
                    c00 = __builtin_amdgcn_mfma_f32_32x32x16_f16(aE[s], B0[s], c00, 0, 0, 0);
                    c10 = __builtin_amdgcn_mfma_f32_32x32x16_f16(aE[s], B1[s], c10, 0, 0, 0);
                }
            }
            f32x16 s0, s1;
            #pragma unroll
            for (int r = 0; r < 16; ++r) { s0[r] = c00[r] + c01[r]; s1[r] = c10[r] + c11[r]; }
            float m0 = tree16(s0), m1 = tree16(s1);
            ins6(__uint_as_float((__float_as_uint(m0) & 0xFFFFFE00u) | idv), gv);
            ins6(__uint_as_float((__float_as_uint(m1) & 0xFFFFFE00u) | idv), hv);
        }
        {   // refill even buffer for g+8
            int gn = (g + 8 < 256) ? (g + 8) : w;
            const f16x8* P = Ahp + (size_t)gn * 576 + l;
            #pragma unroll
            for (int s = 0; s < 9; ++s) aE[s] = P[s * 64];
        }
        // ---- odd sub-iter: tile g+4, id = idv + 8 ----
        {
            f32x16 c00 = {}, c01 = {}, c10 = {}, c11 = {};
            #pragma unroll
            for (int s = 0; s < 9; ++s) {
                if (s & 1) {
                    c01 = __builtin_amdgcn_mfma_f32_32x32x16_f16(aO[s], B0[s], c01, 0, 0, 0);
                    c11 = __builtin_amdgcn_mfma_f32_32x32x16_f16(aO[s], B1[s], c11, 0, 0, 0);
                } else {
                    c00 = __builtin_amdgcn_mfma_f32_32x32x16_f16(aO[s], B0[s], c00, 0, 0, 0);
                    c10 = __builtin_amdgcn_mfma_f32_32x32x16_f16(aO[s], B1[s], c10, 0, 0, 0);
                }
            }
            f32x16 s0, s1;
            #pragma unroll
            for (int r = 0; r < 16; ++r) { s0[r] = c00[r] + c01[r]; s1[r] = c10[r] + c11[r]; }
            float m0 = tree16(s0), m1 = tree16(s1);
            uint32_t ido = idv + 8u;
            ins6(__uint_as_float((__float_as_uint(m0) & 0xFFFFFE00u) | ido), gv);
            ins6(__uint_as_float((__float_as_uint(m1) & 0xFFFFFE00u) | ido), hv);
        }
        {   // refill odd buffer for g+12
            int gn = (g + 12 < 256) ? (g + 12) : w;
            const f16x8* P = Ahp + (size_t)gn * 576 + l;
            #pragma unroll
            for (int s = 0; s < 9; ++s) aO[s] = P[s * 64];
        }
        idv += 16u;
    }

    // ===== Phase 4: cross-wave merge per pixel, write cand (6 groups + z2) =====
    __syncthreads();
    float* Ms = Xs;   // [64 px][8 slots][6]
    const int slot = (w << 1) | half;
    #pragma unroll
    for (int q = 0; q < 6; ++q) {
        Ms[(pcol * 8 + slot) * 6 + q] = gv[q];
        Ms[((32 + pcol) * 8 + slot) * 6 + q] = hv[q];
    }
    __syncthreads();
    if (t < 64) {
        float v6[6] = {3e38f, 3e38f, 3e38f, 3e38f, 3e38f, 3e38f};
        #pragma unroll
        for (int s = 0; s < 48; ++s) ins6(Ms[t * 48 + s], v6);
        float z2 = z2p[t*4+0] + z2p[t*4+1] + z2p[t*4+2] + z2p[t*4+3];
        cand[(size_t)(n0 + t) * 2 + 0] = make_float4(v6[0], v6[1], v6[2], v6[3]);
        cand[(size_t)(n0 + t) * 2 + 1] = make_float4(v6[4], v6[5], z2, 0.f);
    }
}

// ---------------- K3: early-exit exact fp32 over candidate groups ----------------
// 16 lanes per pixel; per code: coalesced load + shfl reduce.
// Packed id decode: id = bits[8:0], tile = id>>1, half = id&1;
// group codes m = tile*32 + half*4 + {(c&3) + 8*(c>>2)}.
__global__ __launch_bounds__(256) void k_rec(
    const float* __restrict__ zws, const float* __restrict__ emb,
    const float4* __restrict__ cand, int* __restrict__ idxws,
    float* __restrict__ out_idxf, float* __restrict__ losssum,
    int* __restrict__ rlist, int* __restrict__ rcnt)
{
    __shared__ float lred[16];
    const int t = threadIdx.x;
    const int pl = t >> 4, j = t & 15;
    const int n = blockIdx.x * 16 + pl;

    const float4 za = *(const float4*)&zws[(size_t)n * 128 + j * 8];
    const float4 zb = *(const float4*)&zws[(size_t)n * 128 + j * 8 + 4];
    const float4 c0 = cand[(size_t)n * 2 + 0];
    const float4 c1 = cand[(size_t)n * 2 + 1];
    const float pv[6] = {c0.x, c0.y, c0.z, c0.w, c1.x, c1.y};
    const float pbase = c1.z - 512.0f;   // d = packed + pbase

    float d1 = 3e38f, d2 = 3e38f; int i1 = 0x7fffffff;
    bool safe = false;
    float lastgmin = 0.f;
    for (int q = 0; q < 6; ++q) {
        uint32_t bits = __float_as_uint(pv[q]);
        float gmin = __uint_as_float(bits & 0xFFFFFE00u);
        lastgmin = gmin;
        if (gmin >= d1 - pbase + EPS_STOP) { safe = true; break; }
        const int mbase = (int)((bits >> 1) & 255u) * 32 + (int)((bits & 1u) << 2); // tile*32 + half*4
        #pragma unroll
        for (int c = 0; c < 16; ++c) {
            int m = mbase + (c & 3) + 8 * (c >> 2);
            const float4 ea = *(const float4*)&emb[(size_t)m * 128 + j * 8];
            const float4 eb = *(const float4*)&emb[(size_t)m * 128 + j * 8 + 4];
            float da0 = za.x - ea.x, da1 = za.y - ea.y, da2 = za.z - ea.z, da3 = za.w - ea.w;
            float db0 = zb.x - eb.x, db1 = zb.y - eb.y, db2 = zb.z - eb.z, db3 = zb.w - eb.w;
            float s = da0*da0; s = fmaf(da1, da1, s); s = fmaf(da2, da2, s); s = fmaf(da3, da3, s);
            s = fmaf(db0, db0, s); s = fmaf(db1, db1, s); s = fmaf(db2, db2, s); s = fmaf(db3, db3, s);
            s += __shfl_xor(s, 1, 16);
            s += __shfl_xor(s, 2, 16);
            s += __shfl_xor(s, 4, 16);
            s += __shfl_xor(s, 8, 16);
            if (s < d1 || (s == d1 && m < i1)) { d2 = d1; d1 = s; i1 = m; }
            else if (s < d2) { d2 = s; }
        }
    }
    if (!safe && lastgmin >= d1 - pbase + EPS_STOP) safe = true;  // post-check vs pv[5]

    if (j == 0) {
        idxws[n] = i1;
        out_idxf[n] = (float)i1;
        if (!safe || (d2 - d1) < TAUF) {
            int s = atomicAdd(rcnt, 1);
            if (s < RCAP) rlist[s] = n;
        }
        lred[pl] = d1;
    }
    __syncthreads();
    if (t == 0) {
        float ls = 0.f;
        #pragma unroll
        for (int q = 0; q < 16; ++q) ls += lred[q];
        atomicAdd(losssum, ls);
    }
}

// ---------------- K4: full exact scan for flagged pixels ----------------
__global__ __launch_bounds__(128) void k_scan(
    const float* __restrict__ x, const float* __restrict__ Wl, const float* __restrict__ bl,
    const float* __restrict__ emb, const int* __restrict__ rcnt, const int* __restrict__ rlist,
    int* __restrict__ idxws, float* __restrict__ out_idxf)
{
    __shared__ double xs[128];
    __shared__ double zd[128];
    __shared__ __align__(16) float zf[128];
    __shared__ double red[128];
    __shared__ float red32[128];
    __shared__ int nl;
    __shared__ int clist[16];
    int cnt = *rcnt; if (cnt > RCAP) cnt = RCAP;
    const int t = threadIdx.x;
    for (int e = blockIdx.x; e < cnt; e += gridDim.x) {
        const int n = rlist[e];
        const int b = n >> 10, hw = n & 1023;
        __syncthreads();
        xs[t] = (double)x[(size_t)(b * 128 + t) * 1024 + hw];
        if (t == 0) nl = 0;
        __syncthreads();
        double z = (double)bl[t];
        for (int c = 0; c < 128; ++c) z = fma((double)Wl[(size_t)t * 128 + c], xs[c], z);
        zd[t] = z; zf[t] = (float)z;
        __syncthreads();
        float dmin = 3e38f;
        for (int k = t; k < KCB; k += 128) {
            const float4* ep = (const float4*)&emb[(size_t)k * 128];
            float d = 0.f;
            #pragma unroll 8
            for (int c4 = 0; c4 < 32; ++c4) {
                float4 e4 = ep[c4];
                float4 z4 = *(const float4*)&zf[c4 * 4];
                float d0 = z4.x - e4.x, d1 = z4.y - e4.y, d2 = z4.z - e4.z, d3 = z4.w - e4.w;
                d = fmaf(d0, d0, fmaf(d1, d1, fmaf(d2, d2, fmaf(d3, d3, d))));
            }
            dmin = fminf(dmin, d);
        }
        red32[t] = dmin; __syncthreads();
        for (int o = 64; o; o >>= 1) { if (t < o) red32[t] = fminf(red32[t], red32[t + o]); __syncthreads(); }
        float dblk = red32[0];
        for (int k = t; k < KCB; k += 128) {
            const float4* ep = (const float4*)&emb[(size_t)k * 128];
            float d = 0.f;
            #pragma unroll 8
            for (int c4 = 0; c4 < 32; ++c4) {
                float4 e4 = ep[c4];
                float4 z4 = *(const float4*)&zf[c4 * 4];
                float d0 = z4.x - e4.x, d1 = z4.y - e4.y, d2 = z4.z - e4.z, d3 = z4.w - e4.w;
                d = fmaf(d0, d0, fmaf(d1, d1, fmaf(d2, d2, fmaf(d3, d3, d))));
            }
            if (d < dblk + 0.05f) { int p = atomicAdd(&nl, 1); if (p < 16) clist[p] = k; }
        }
        __syncthreads();
        int c2 = nl < 16 ? nl : 16;
        double bd = 1e300; int bi = KCB;
        for (int q = 0; q < c2; ++q) {
            int k = clist[q];
            double df = zd[t] - (double)emb[(size_t)k * 128 + t];
            red[t] = df * df; __syncthreads();
            for (int o = 64; o; o >>= 1) { if (t < o) red[t] += red[t + o]; __syncthreads(); }
            double d = red[0]; __syncthreads();
            if (d < bd || (d == bd && k < bi)) { bd = d; bi = k; }
        }
        if (t == 0) { idxws[n] = bi; out_idxf[n] = (float)bi; }
    }
}

// ---------------- K5: gather + transpose + histogram ----------------
__global__ __launch_bounds__(256) void k_out(
    const float* __restrict__ emb, const int* __restrict__ idxws,
    float* __restrict__ outp /* d_out + 1 */, float* __restrict__ counts)
{
    const int t = threadIdx.x;
    const int b = blockIdx.x >> 2, h0 = (blockIdx.x & 3) << 3;
    const int n = b * 1024 + h0 * 32 + t;
    const int id = idxws[n];
    atomicAdd(&counts[id], 1.0f);
    const float4* ep = (const float4*)&emb[(size_t)id * 128];
    float* ob = outp + (size_t)b * 131072 + h0 * 32 + t;
    #pragma unroll 4
    for (int c4 = 0; c4 < 32; ++c4) {
        float4 v = ep[c4];
        ob[(c4 * 4 + 0) * 1024] = v.x;
        ob[(c4 * 4 + 1) * 1024] = v.y;
        ob[(c4 * 4 + 2) * 1024] = v.z;
        ob[(c4 * 4 + 3) * 1024] = v.w;
    }
}

// ---------------- K6: finalize loss + perplexity ----------------
__global__ __launch_bounds__(256) void k_final(
    const float* __restrict__ counts, const float* __restrict__ losssum, float* __restrict__ d_out)
{
    const int t = threadIdx.x;
    float ent = 0.f;
    for (int k = t; k < KCB; k += 256) {
        float p = counts[k] * (1.0f / 32768.0f);
        ent -= p * logf(p + 1e-10f);
    }
    #pragma unroll
    for (int o = 32; o; o >>= 1) ent += __shfl_down(ent, o, 64);
    __shared__ float wred[4];
    if ((t & 63) == 0) wred[t >> 6] = ent;
    __syncthreads();
    if (t == 0) {
        float e = wred[0] + wred[1] + wred[2] + wred[3];
        d_out[0] = 1.25f * (*losssum) * (1.0f / 4194304.0f);
        d_out[OUT_OFF_PERP] = expf(e);
    }
}

extern "C" void kernel_launch(void* const* d_in, const int* in_sizes, int n_in,
                              void* d_out, int out_size, void* d_ws, size_t ws_size,
                              hipStream_t stream) {
    (void)in_sizes; (void)n_in; (void)out_size; (void)ws_size;
    const float* x   = (const float*)d_in[0];
    const float* Wl  = (const float*)d_in[1];
    const float* bl  = (const float*)d_in[2];
    const float* emb = (const float*)d_in[3];
    float* out = (float*)d_out;
    char*  ws  = (char*)d_ws;

    _Float16* embFh = (_Float16*)(ws + WS_EMBFH);
    float* e2      = (float*)(ws + WS_E2);
    float* zws     = (float*)(ws + WS_ZWS);
    float4* cand   = (float4*)(ws + WS_CAND);
    int*   idxws   = (int*)  (ws + WS_IDX);
    int*   rlist   = (int*)  (ws + WS_RLIST);
    float* counts  = (float*)(ws + WS_COUNTS);
    float* losssum = (float*)(ws + WS_LOSS);
    int*   rcnt    = (int*)  (ws + WS_RCNT);

    hipMemsetAsync(ws + WS_ZERO_OFF, 0, WS_ZERO_LEN, stream);

    k_e2<<<KCB / 4, 256, 0, stream>>>(emb, e2);
    k_prep<<<576, 256, 0, stream>>>(emb, e2, embFh);
    k_main<<<NPIX / 64, 256, 0, stream>>>(x, Wl, bl, embFh, zws, cand);
    k_rec<<<NPIX / 16, 256, 0, stream>>>(zws, emb, cand, idxws, out + OUT_OFF_IDX,
                                         losssum, rlist, rcnt);
    k_scan<<<512, 128, 0, stream>>>(x, Wl, bl, emb, rcnt, rlist, idxws, out + OUT_OFF_IDX);
    k_out<<<128, 256, 0, stream>>>(emb, idxws, out + OUT_OFF_OUT, counts);
    k_final<<<1, 256, 0, stream>>>(counts, losssum, out);
}

// Round 7
// 309.615 us; speedup vs baseline: 2.0207x; 1.7792x over previous
//
#include <hip/hip_runtime.h>
#include <hip/hip_bf16.h>
#include <float.h>

// Problem constants
#define NPIX   32768      // B*H*W
#define CDIM   128
#define KCB    8192
#define EPS_STOP 0.30f    // mask quant (0.031) + f16-dot error bound
#define TAUF   0.012f     // exact fp32 gap guard -> fp64 arbitration
#define RCAP   8192
#define RCAPA  2048

typedef _Float16 f16x8 __attribute__((ext_vector_type(8)));
typedef float    f32x16 __attribute__((ext_vector_type(16)));

// ws layout (bytes)
#define WS_EMBFH   0           // 2,359,296
#define WS_E2      2359296     // 32,768
#define WS_ZWS     2392064     // 16,777,216
#define WS_CAND    19169280    // 1,048,576
#define WS_IDX     20217856    // 131,072
#define WS_RLISTA  20348928    // 32,768 (cap 2048 used)
#define WS_RLISTB  20381696    // 131,072 (8192 * int4)
#define WS_SCAND   20512768    // 524,288 (2048*32 double)
#define WS_SCANI   21037056    // 262,144 (2048*32 int)
#define WS_COUNTS  21299200    // 32,768
#define WS_LOSS    21331968    // 4
#define WS_RCNTA   21331972    // 4
#define WS_RCNTB   21331976    // 4
#define WS_ZERO_OFF 21299200
#define WS_ZERO_LEN 32780

// d_out layout (f32): [0]=loss, [1..4194304]=out BCHW, [4194305]=perplexity, [4194306..]=idx
#define OUT_OFF_OUT  1
#define OUT_OFF_PERP 4194305
#define OUT_OFF_IDX  4194306

__device__ __forceinline__ void ins6(float f, float v[6]) {
    float a = fmaxf(v[0], f); v[0] = fminf(v[0], f);
    float b = fmaxf(v[1], a); v[1] = fminf(v[1], a);
    a = fmaxf(v[2], b); v[2] = fminf(v[2], b);
    b = fmaxf(v[3], a); v[3] = fminf(v[3], a);
    a = fmaxf(v[4], b); v[4] = fminf(v[4], b);
    v[5] = fminf(v[5], a);
}

// ---------------- K0: e2[k] = sum_c emb[k][c]^2 ----------------
__global__ __launch_bounds__(256) void k_e2(const float* __restrict__ emb, float* __restrict__ e2) {
    int t = threadIdx.x;
    int wv = t >> 6, l = t & 63;
    int k = blockIdx.x * 4 + wv;
    const float2 v = *(const float2*)&emb[(size_t)k * 128 + l * 2];
    float s = v.x * v.x + v.y * v.y;
    #pragma unroll
    for (int o = 32; o; o >>= 1) s += __shfl_down(s, o, 64);
    if (l == 0) e2[k] = s;
}

// ---------------- K1: fragment-ordered -2*emb (f16), e2+512 hi/lo fold in step 8 ----------------
__global__ __launch_bounds__(256) void k_prep(const float* __restrict__ emb, const float* __restrict__ e2,
                                              _Float16* __restrict__ embFh) {
    int tid = blockIdx.x * 256 + threadIdx.x;   // < 147456 = 8192*18
    int m = tid / 18, r = tid % 18;
    int s = r >> 1, h = r & 1;
    f16x8 hv;
    #pragma unroll
    for (int j = 0; j < 8; ++j) hv[j] = (_Float16)0.0f;
    if (s < 8) {
        int c0 = s * 16 + h * 8;
        const float4 a = *(const float4*)&emb[(size_t)m * 128 + c0];
        const float4 b = *(const float4*)&emb[(size_t)m * 128 + c0 + 4];
        float vals[8] = {a.x, a.y, a.z, a.w, b.x, b.y, b.z, b.w};
        #pragma unroll
        for (int j = 0; j < 8; ++j) hv[j] = (_Float16)(-2.0f * vals[j]);
    } else if (h == 0) {
        float v = e2[m] + 512.0f;    // offset keeps packed values > 0 (z2 dropped)
        _Float16 eh = (_Float16)v;
        hv[0] = eh;                  // x B8[0]=1
        hv[1] = (_Float16)(v - (float)eh);   // x B8[1]=1
    }
    size_t base = (((size_t)(m >> 5) * 9 + s) * 64 + (m & 31) + h * 32) * 8;
    *(f16x8*)&embFh[base] = hv;
}

// ---------------- K2: fused linear + MFMA + packed group-min top-6 ----------------
__global__ __launch_bounds__(256, 2) void k_main(
    const float* __restrict__ x, const float* __restrict__ Wl, const float* __restrict__ bl,
    const _Float16* __restrict__ embFh,
    float* __restrict__ zws, float4* __restrict__ cand)
{
    __shared__ __align__(16) float As[64 * 132];   // z [p][c], pitch 132
    __shared__ __align__(16) float Xs[64 * 66];    // x staging / merge scratch
    __shared__ float z2p[256];                      // z^2 partials [p][ig]

    const int t  = threadIdx.x;
    const int n0 = blockIdx.x * 64;
    const int b  = n0 >> 10;
    const int hw0 = n0 & 1023;

    // ===== Phase 1: z for 64 pixels =====
    {
        const int p = t & 63, ig = t >> 6;
        float accz[32];
        const float4* bl4 = (const float4*)(bl + ig * 32);
        #pragma unroll
        for (int q = 0; q < 8; ++q) {
            float4 v = bl4[q];
            accz[4*q+0] = v.x; accz[4*q+1] = v.y; accz[4*q+2] = v.z; accz[4*q+3] = v.w;
        }
        for (int hf = 0; hf < 2; ++hf) {
            __syncthreads();
            for (int r = 0; r < 16; ++r) {
                int lin = r * 256 + t;
                int cc = lin >> 6, pp = lin & 63;
                Xs[cc * 66 + pp] = x[(size_t)(b * 128 + hf * 64 + cc) * 1024 + hw0 + pp];
            }
            __syncthreads();
            for (int cc4 = 0; cc4 < 16; ++cc4) {
                float xv0 = Xs[(cc4*4+0) * 66 + p];
                float xv1 = Xs[(cc4*4+1) * 66 + p];
                float xv2 = Xs[(cc4*4+2) * 66 + p];
                float xv3 = Xs[(cc4*4+3) * 66 + p];
                #pragma unroll
                for (int ii = 0; ii < 32; ++ii) {
                    const float4 w4 = *(const float4*)&Wl[(size_t)(ig*32+ii) * 128 + hf*64 + cc4*4];
                    float a = accz[ii];
                    a = fmaf(w4.x, xv0, a);
                    a = fmaf(w4.y, xv1, a);
                    a = fmaf(w4.z, xv2, a);
                    a = fmaf(w4.w, xv3, a);
                    accz[ii] = a;
                }
            }
        }
        float ssq = 0.f;
        float4* ao = (float4*)&As[p * 132 + ig * 32];
        float4* zo = (float4*)(zws + (size_t)(n0 + p) * 128 + ig * 32);
        #pragma unroll
        for (int q = 0; q < 8; ++q) {
            float4 v = make_float4(accz[4*q+0], accz[4*q+1], accz[4*q+2], accz[4*q+3]);
            ao[q] = v;
            zo[q] = v;
            ssq = fmaf(v.x, v.x, fmaf(v.y, v.y, fmaf(v.z, v.z, fmaf(v.w, v.w, ssq))));
        }
        z2p[p * 4 + ig] = ssq;
    }
    __syncthreads();

    // ===== Phase 2: B fragments (z f16) + constant fold step =====
    const int l = t & 63, w = t >> 6;
    const int half = l >> 5, pcol = l & 31;
    f16x8 B0[9], B1[9];
    #pragma unroll
    for (int nt = 0; nt < 2; ++nt) {
        int p = nt * 32 + pcol;
        #pragma unroll
        for (int s = 0; s < 8; ++s) {
            const float* zp = &As[p * 132 + s * 16 + half * 8];
            float4 v0 = *(const float4*)zp;
            float4 v1 = *(const float4*)(zp + 4);
            float vals[8] = {v0.x, v0.y, v0.z, v0.w, v1.x, v1.y, v1.z, v1.w};
            f16x8 hh;
            #pragma unroll
            for (int j2 = 0; j2 < 8; ++j2) hh[j2] = (_Float16)vals[j2];
            if (nt == 0) B0[s] = hh; else B1[s] = hh;
        }
    }
    {
        f16x8 b8;
        #pragma unroll
        for (int j2 = 0; j2 < 8; ++j2) b8[j2] = (_Float16)0.0f;
        if (half == 0) { b8[0] = (_Float16)1.0f; b8[1] = (_Float16)1.0f; }
        B0[8] = b8; B1[8] = b8;
    }

    // ===== Phase 3: K-loop, even/odd A double-buffer, 4 acc chains, top-6 groups =====
    auto tree16 = [](const f32x16& v) -> float {
        float a = fminf(fminf(v[0], v[1]), fminf(v[2], v[3]));
        float bb = fminf(fminf(v[4], v[5]), fminf(v[6], v[7]));
        float c = fminf(fminf(v[8], v[9]), fminf(v[10], v[11]));
        float d = fminf(fminf(v[12], v[13]), fminf(v[14], v[15]));
        return fminf(fminf(a, bb), fminf(c, d));
    };

    float gv[6] = {3e38f, 3e38f, 3e38f, 3e38f, 3e38f, 3e38f};   // tile0: px = pcol
    float hv[6] = {3e38f, 3e38f, 3e38f, 3e38f, 3e38f, 3e38f};   // tile1: px = 32+pcol
    const f16x8* Ahp = (const f16x8*)embFh;
    f16x8 aE[9], aO[9];
    {
        const f16x8* P = Ahp + (size_t)w * 576 + l;
        #pragma unroll
        for (int s = 0; s < 9; ++s) aE[s] = P[s * 64];
    }
    {
        const f16x8* P = Ahp + (size_t)(w + 4) * 576 + l;
        #pragma unroll
        for (int s = 0; s < 9; ++s) aO[s] = P[s * 64];
    }
    uint32_t idv = (uint32_t)((w << 1) | half);

    for (int g = w; g < 256; g += 8) {
        // ---- even sub-iter: tile g, id = idv ----
        {
            f32x16 c00 = {}, c01 = {}, c10 = {}, c11 = {};
            #pragma unroll
            for (int s = 0; s < 9; ++s) {
                if (s & 1) {
                    c01 = __builtin_amdgcn_mfma_f32_32x32x16_f16(aE[s], B0[s], c01, 0, 0, 0);
                    c11 = __builtin_amdgcn_mfma_f32_32x32x16_f16(aE[s], B1[s], c11, 0, 0, 0);
                } else {
                    c00 = __builtin_amdgcn_mfma_f32_32x32x16_f16(aE[s], B0[s], c00, 0, 0, 0);
                    c10 = __builtin_amdgcn_mfma_f32_32x32x16_f16(aE[s], B1[s], c10, 0, 0, 0);
                }
            }
            f32x16 s0, s1;
            #pragma unroll
            for (int r = 0; r < 16; ++r) { s0[r] = c00[r] + c01[r]; s1[r] = c10[r] + c11[r]; }
            float m0 = tree16(s0), m1 = tree16(s1);
            ins6(__uint_as_float((__float_as_uint(m0) & 0xFFFFFE00u) | idv), gv);
            ins6(__uint_as_float((__float_as_uint(m1) & 0xFFFFFE00u) | idv), hv);
        }
        {   // refill even buffer for g+8
            int gn = (g + 8 < 256) ? (g + 8) : w;
            const f16x8* P = Ahp + (size_t)gn * 576 + l;
            #pragma unroll
            for (int s = 0; s < 9; ++s) aE[s] = P[s * 64];
        }
        // ---- odd sub-iter: tile g+4, id = idv + 8 ----
        {
            f32x16 c00 = {}, c01 = {}, c10 = {}, c11 = {};
            #pragma unroll
            for (int s = 0; s < 9; ++s) {
                if (s & 1) {
                    c01 = __builtin_amdgcn_mfma_f32_32x32x16_f16(aO[s], B0[s], c01, 0, 0, 0);
                    c11 = __builtin_amdgcn_mfma_f32_32x32x16_f16(aO[s], B1[s], c11, 0, 0, 0);
                } else {
                    c00 = __builtin_amdgcn_mfma_f32_32x32x16_f16(aO[s], B0[s], c00, 0, 0, 0);
                    c10 = __builtin_amdgcn_mfma_f32_32x32x16_f16(aO[s], B1[s], c10, 0, 0, 0);
                }
            }
            f32x16 s0, s1;
            #pragma unroll
            for (int r = 0; r < 16; ++r) { s0[r] = c00[r] + c01[r]; s1[r] = c10[r] + c11[r]; }
            float m0 = tree16(s0), m1 = tree16(s1);
            uint32_t ido = idv + 8u;
            ins6(__uint_as_float((__float_as_uint(m0) & 0xFFFFFE00u) | ido), gv);
            ins6(__uint_as_float((__float_as_uint(m1) & 0xFFFFFE00u) | ido), hv);
        }
        {   // refill odd buffer for g+12
            int gn = (g + 12 < 256) ? (g + 12) : w;
            const f16x8* P = Ahp + (size_t)gn * 576 + l;
            #pragma unroll
            for (int s = 0; s < 9; ++s) aO[s] = P[s * 64];
        }
        idv += 16u;
    }

    // ===== Phase 4: cross-wave merge per pixel, write cand (6 groups + z2) =====
    __syncthreads();
    float* Ms = Xs;   // [64 px][8 slots][6]
    const int slot = (w << 1) | half;
    #pragma unroll
    for (int q = 0; q < 6; ++q) {
        Ms[(pcol * 8 + slot) * 6 + q] = gv[q];
        Ms[((32 + pcol) * 8 + slot) * 6 + q] = hv[q];
    }
    __syncthreads();
    if (t < 64) {
        float v6[6] = {3e38f, 3e38f, 3e38f, 3e38f, 3e38f, 3e38f};
        #pragma unroll
        for (int s = 0; s < 48; ++s) ins6(Ms[t * 48 + s], v6);
        float z2 = z2p[t*4+0] + z2p[t*4+1] + z2p[t*4+2] + z2p[t*4+3];
        cand[(size_t)(n0 + t) * 2 + 0] = make_float4(v6[0], v6[1], v6[2], v6[3]);
        cand[(size_t)(n0 + t) * 2 + 1] = make_float4(v6[4], v6[5], z2, 0.f);
    }
}

// ---------------- K3: early-exit exact fp32 over candidate groups ----------------
// Packed id decode: id = bits[8:0], tile = id>>1, half = id&1;
// group codes m = tile*32 + half*4 + {(c&3) + 8*(c>>2)}.
// Flags: !safe -> rlistA (parallel full scan); near-tie -> rlistB (fp64 pair arb).
__global__ __launch_bounds__(256) void k_rec(
    const float* __restrict__ zws, const float* __restrict__ emb,
    const float4* __restrict__ cand, int* __restrict__ idxws,
    float* __restrict__ out_idxf, float* __restrict__ losssum,
    int* __restrict__ rlistA, int* __restrict__ rcntA,
    int* __restrict__ rlistB, int* __restrict__ rcntB)
{
    __shared__ float lred[16];
    const int t = threadIdx.x;
    const int pl = t >> 4, j = t & 15;
    const int n = blockIdx.x * 16 + pl;

    const float4 za = *(const float4*)&zws[(size_t)n * 128 + j * 8];
    const float4 zb = *(const float4*)&zws[(size_t)n * 128 + j * 8 + 4];
    const float4 c0 = cand[(size_t)n * 2 + 0];
    const float4 c1 = cand[(size_t)n * 2 + 1];
    const float pv[6] = {c0.x, c0.y, c0.z, c0.w, c1.x, c1.y};
    const float pbase = c1.z - 512.0f;   // d = packed + pbase

    float d1 = 3e38f, d2 = 3e38f; int i1 = 0x7fffffff, i2 = 0x7fffffff;
    bool safe = false;
    float lastgmin = 0.f;
    for (int q = 0; q < 6; ++q) {
        uint32_t bits = __float_as_uint(pv[q]);
        float gmin = __uint_as_float(bits & 0xFFFFFE00u);
        lastgmin = gmin;
        if (gmin >= d1 - pbase + EPS_STOP) { safe = true; break; }
        const int mbase = (int)((bits >> 1) & 255u) * 32 + (int)((bits & 1u) << 2); // tile*32 + half*4
        #pragma unroll
        for (int c = 0; c < 16; ++c) {
            int m = mbase + (c & 3) + 8 * (c >> 2);
            const float4 ea = *(const float4*)&emb[(size_t)m * 128 + j * 8];
            const float4 eb = *(const float4*)&emb[(size_t)m * 128 + j * 8 + 4];
            float da0 = za.x - ea.x, da1 = za.y - ea.y, da2 = za.z - ea.z, da3 = za.w - ea.w;
            float db0 = zb.x - eb.x, db1 = zb.y - eb.y, db2 = zb.z - eb.z, db3 = zb.w - eb.w;
            float s = da0*da0; s = fmaf(da1, da1, s); s = fmaf(da2, da2, s); s = fmaf(da3, da3, s);
            s = fmaf(db0, db0, s); s = fmaf(db1, db1, s); s = fmaf(db2, db2, s); s = fmaf(db3, db3, s);
            s += __shfl_xor(s, 1, 16);
            s += __shfl_xor(s, 2, 16);
            s += __shfl_xor(s, 4, 16);
            s += __shfl_xor(s, 8, 16);
            if (s < d1 || (s == d1 && m < i1)) { d2 = d1; i2 = i1; d1 = s; i1 = m; }
            else if (s < d2) { d2 = s; i2 = m; }
        }
    }
    if (!safe && lastgmin >= d1 - pbase + EPS_STOP) safe = true;  // post-check vs pv[5]

    if (j == 0) {
        idxws[n] = i1;
        out_idxf[n] = (float)i1;
        if (!safe) {
            int s = atomicAdd(rcntA, 1);
            if (s < RCAPA) rlistA[s] = n;
        } else if ((d2 - d1) < TAUF) {
            int s = atomicAdd(rcntB, 1);
            if (s < RCAP) { int4 v4 = make_int4(n, i1, i2, 0); ((int4*)rlistB)[s] = v4; }
        }
        lred[pl] = d1;
    }
    __syncthreads();
    if (t == 0) {
        float ls = 0.f;
        #pragma unroll
        for (int q = 0; q < 16; ++q) ls += lred[q];
        atomicAdd(losssum, ls);
    }
}

// ---------------- K4a: parallel full scan for !safe pixels ----------------
// 32 chunk-blocks per pixel, 256 codes/chunk; 16 lanes/code coalesced; fp64 accum.
__global__ __launch_bounds__(256) void k_scanp(
    const float* __restrict__ zws, const float* __restrict__ emb,
    const int* __restrict__ rcntA, const int* __restrict__ rlistA,
    double* __restrict__ scand, int* __restrict__ scani)
{
    int cnt = *rcntA; if (cnt > RCAPA) cnt = RCAPA;
    const int t = threadIdx.x;
    const int chunk = blockIdx.x & 31;
    const int gi = t >> 4, j = t & 15;
    __shared__ double sd[16];
    __shared__ int si[16];
    for (int e = blockIdx.x >> 5; e < cnt; e += 64) {
        const int n = rlistA[e];
        const float4 za = *(const float4*)&zws[(size_t)n * 128 + j * 8];
        const float4 zb = *(const float4*)&zws[(size_t)n * 128 + j * 8 + 4];
        double best = 1e300; int bi = 0x7fffffff;
        const int kbase = chunk * 256 + gi * 16;
        for (int c = 0; c < 16; ++c) {
            const int m = kbase + c;
            const float4 ea = *(const float4*)&emb[(size_t)m * 128 + j * 8];
            const float4 eb = *(const float4*)&emb[(size_t)m * 128 + j * 8 + 4];
            double s = 0.0, d;
            d = (double)za.x - (double)ea.x; s += d * d;
            d = (double)za.y - (double)ea.y; s += d * d;
            d = (double)za.z - (double)ea.z; s += d * d;
            d = (double)za.w - (double)ea.w; s += d * d;
            d = (double)zb.x - (double)eb.x; s += d * d;
            d = (double)zb.y - (double)eb.y; s += d * d;
            d = (double)zb.z - (double)eb.z; s += d * d;
            d = (double)zb.w - (double)eb.w; s += d * d;
            s += __shfl_xor(s, 1, 16);
            s += __shfl_xor(s, 2, 16);
            s += __shfl_xor(s, 4, 16);
            s += __shfl_xor(s, 8, 16);
            if (s < best) { best = s; bi = m; }   // m strictly increasing -> first-index
        }
        __syncthreads();
        if (j == 0) { sd[gi] = best; si[gi] = bi; }
        __syncthreads();
        if (t == 0) {
            double b = sd[0]; int ib = si[0];
            #pragma unroll
            for (int q = 1; q < 16; ++q)
                if (sd[q] < b || (sd[q] == b && si[q] < ib)) { b = sd[q]; ib = si[q]; }
            scand[e * 32 + chunk] = b;
            scani[e * 32 + chunk] = ib;
        }
    }
}

// ---------------- K4b: merge 32 chunk results per !safe pixel ----------------
__global__ __launch_bounds__(64) void k_mergeA(
    const int* __restrict__ rcntA, const int* __restrict__ rlistA,
    const double* __restrict__ scand, const int* __restrict__ scani,
    int* __restrict__ idxws, float* __restrict__ out_idxf)
{
    int cnt = *rcntA; if (cnt > RCAPA) cnt = RCAPA;
    const int t = threadIdx.x;
    for (int e = blockIdx.x; e < cnt; e += gridDim.x) {
        double b = 1e300; int ib = 0x7fffffff;
        if (t < 32) { b = scand[e * 32 + t]; ib = scani[e * 32 + t]; }
        #pragma unroll
        for (int o = 16; o; o >>= 1) {
            double ob = __shfl_down(b, o, 64);
            int oi = __shfl_down(ib, o, 64);
            if (ob < b || (ob == b && oi < ib)) { b = ob; ib = oi; }
        }
        if (t == 0) { int n = rlistA[e]; idxws[n] = ib; out_idxf[n] = (float)ib; }
    }
}

// ---------------- K4c: fp64 pair arbitration for near-tie pixels ----------------
__global__ __launch_bounds__(128) void k_pairB(
    const float* __restrict__ x, const float* __restrict__ Wl, const float* __restrict__ bl,
    const float* __restrict__ emb, const int* __restrict__ rcntB, const int* __restrict__ rlistB,
    int* __restrict__ idxws, float* __restrict__ out_idxf)
{
    __shared__ double xs[128];
    __shared__ double red[128];
    int cnt = *rcntB; if (cnt > RCAP) cnt = RCAP;
    const int t = threadIdx.x;
    for (int e = blockIdx.x; e < cnt; e += gridDim.x) {
        const int4 v = ((const int4*)rlistB)[e];
        const int n = v.x, c1 = v.y, c2 = v.z;
        const int b = n >> 10, hw = n & 1023;
        __syncthreads();
        xs[t] = (double)x[(size_t)(b * 128 + t) * 1024 + hw];
        __syncthreads();
        double z = (double)bl[t];
        for (int c = 0; c < 128; ++c) z = fma((double)Wl[(size_t)t * 128 + c], xs[c], z);
        double d1v, d2v;
        double da = z - (double)emb[(size_t)c1 * 128 + t];
        red[t] = da * da; __syncthreads();
        for (int o = 64; o; o >>= 1) { if (t < o) red[t] += red[t + o]; __syncthreads(); }
        d1v = red[0]; __syncthreads();
        double db = z - (double)emb[(size_t)c2 * 128 + t];
        red[t] = db * db; __syncthreads();
        for (int o = 64; o; o >>= 1) { if (t < o) red[t] += red[t + o]; __syncthreads(); }
        d2v = red[0];
        if (t == 0) {
            int win = (d2v < d1v || (d2v == d1v && c2 < c1)) ? c2 : c1;
            idxws[n] = win;
            out_idxf[n] = (float)win;
        }
        __syncthreads();
    }
}

// ---------------- K5: gather + transpose + histogram ----------------
__global__ __launch_bounds__(256) void k_out(
    const float* __restrict__ emb, const int* __restrict__ idxws,
    float* __restrict__ outp /* d_out + 1 */, float* __restrict__ counts)
{
    const int t = threadIdx.x;
    const int b = blockIdx.x >> 2, h0 = (blockIdx.x & 3) << 3;
    const int n = b * 1024 + h0 * 32 + t;
    const int id = idxws[n];
    atomicAdd(&counts[id], 1.0f);
    const float4* ep = (const float4*)&emb[(size_t)id * 128];
    float* ob = outp + (size_t)b * 131072 + h0 * 32 + t;
    #pragma unroll 4
    for (int c4 = 0; c4 < 32; ++c4) {
        float4 v = ep[c4];
        ob[(c4 * 4 + 0) * 1024] = v.x;
        ob[(c4 * 4 + 1) * 1024] = v.y;
        ob[(c4 * 4 + 2) * 1024] = v.z;
        ob[(c4 * 4 + 3) * 1024] = v.w;
    }
}

// ---------------- K6: finalize loss + perplexity ----------------
__global__ __launch_bounds__(256) void k_final(
    const float* __restrict__ counts, const float* __restrict__ losssum, float* __restrict__ d_out)
{
    const int t = threadIdx.x;
    float ent = 0.f;
    for (int k = t; k < KCB; k += 256) {
        float p = counts[k] * (1.0f / 32768.0f);
        ent -= p * logf(p + 1e-10f);
    }
    #pragma unroll
    for (int o = 32; o; o >>= 1) ent += __shfl_down(ent, o, 64);
    __shared__ float wred[4];
    if ((t & 63) == 0) wred[t >> 6] = ent;
    __syncthreads();
    if (t == 0) {
        float e = wred[0] + wred[1] + wred[2] + wred[3];
        d_out[0] = 1.25f * (*losssum) * (1.0f / 4194304.0f);
        d_out[OUT_OFF_PERP] = expf(e);
    }
}

extern "C" void kernel_launch(void* const* d_in, const int* in_sizes, int n_in,
                              void* d_out, int out_size, void* d_ws, size_t ws_size,
                              hipStream_t stream) {
    (void)in_sizes; (void)n_in; (void)out_size; (void)ws_size;
    const float* x   = (const float*)d_in[0];
    const float* Wl  = (const float*)d_in[1];
    const float* bl  = (const float*)d_in[2];
    const float* emb = (const float*)d_in[3];
    float* out = (float*)d_out;
    char*  ws  = (char*)d_ws;

    _Float16* embFh = (_Float16*)(ws + WS_EMBFH);
    float* e2      = (float*)(ws + WS_E2);
    float* zws     = (float*)(ws + WS_ZWS);
    float4* cand   = (float4*)(ws + WS_CAND);
    int*   idxws   = (int*)  (ws + WS_IDX);
    int*   rlistA  = (int*)  (ws + WS_RLISTA);
    int*   rlistB  = (int*)  (ws + WS_RLISTB);
    double* scand  = (double*)(ws + WS_SCAND);
    int*   scani   = (int*)  (ws + WS_SCANI);
    float* counts  = (float*)(ws + WS_COUNTS);
    float* losssum = (float*)(ws + WS_LOSS);
    int*   rcntA   = (int*)  (ws + WS_RCNTA);
    int*   rcntB   = (int*)  (ws + WS_RCNTB);

    hipMemsetAsync(ws + WS_ZERO_OFF, 0, WS_ZERO_LEN, stream);

    k_e2<<<KCB / 4, 256, 0, stream>>>(emb, e2);
    k_prep<<<576, 256, 0, stream>>>(emb, e2, embFh);
    k_main<<<NPIX / 64, 256, 0, stream>>>(x, Wl, bl, embFh, zws, cand);
    k_rec<<<NPIX / 16, 256, 0, stream>>>(zws, emb, cand, idxws, out + OUT_OFF_IDX,
                                         losssum, rlistA, rcntA, rlistB, rcntB);
    k_scanp<<<2048, 256, 0, stream>>>(zws, emb, rcntA, rlistA, scand, scani);
    k_mergeA<<<32, 64, 0, stream>>>(rcntA, rlistA, scand, scani, idxws, out + OUT_OFF_IDX);
    k_pairB<<<256, 128, 0, stream>>>(x, Wl, bl, emb, rcntB, rlistB, idxws, out + OUT_OFF_IDX);
    k_out<<<128, 256, 0, stream>>>(emb, idxws, out + OUT_OFF_OUT, counts);
    k_final<<<1, 256, 0, stream>>>(counts, losssum, out);
}